// Round 1
// baseline (1281.099 us; speedup 1.0000x reference)
//
#include <hip/hip_runtime.h>
#include <hip/hip_bf16.h>

#define NROWS 100000
#define NH 8

typedef short s16x8 __attribute__((ext_vector_type(8)));
typedef float f32x4 __attribute__((ext_vector_type(4)));
typedef unsigned short u16;

__device__ __forceinline__ u16 f2bf(float f) {
  union { float f; unsigned u; } x; x.f = f;
  unsigned r = (x.u + 0x7FFFu + ((x.u >> 16) & 1u)) >> 16;
  return (u16)r;
}
__device__ __forceinline__ float bf2f(u16 b) {
  union { unsigned u; float f; } x; x.u = ((unsigned)b) << 16;
  return x.f;
}

// ---------------------------------------------------------------------------
// Kernel 1: fused per-head GEMM (q|k|v, 64 rows x 192 cols, K=256, bf16 MFMA)
// + phi feature-map epilogue. Writes phi_q, phi_k, v as bf16 [N,8,64].
// ---------------------------------------------------------------------------
union K1Smem {
  struct { u16 As[64][72]; u16 WsT[192][72]; } s; // 9216 + 27648 B
  float C[64][196];                                // 50176 B (padded: 196%32=4)
};

__global__ __launch_bounds__(256) void k1_gemm_phi(
    const float* __restrict__ x,
    const float* __restrict__ Wq, const float* __restrict__ bq,
    const float* __restrict__ Wk, const float* __restrict__ bk,
    const float* __restrict__ Wv, const float* __restrict__ bv,
    const float* __restrict__ nsc,
    u16* __restrict__ phi_q, u16* __restrict__ phi_k, u16* __restrict__ vout)
{
  __shared__ K1Smem u;
  __shared__ float bias[192];
  __shared__ float scl[64][2];

  const int tid = threadIdx.x;
  const int h = blockIdx.y;
  const int n0 = blockIdx.x * 64;
  const int wave = tid >> 6;
  const int lane = tid & 63;

  if (tid < 192) {
    float b;
    if (tid < 64) b = bq[h * 64 + tid];
    else if (tid < 128) b = bk[h * 64 + tid - 64];
    else b = bv[h * 64 + tid - 128];
    bias[tid] = b;
  }

  f32x4 zero4 = {0.f, 0.f, 0.f, 0.f};
  f32x4 acc[12];
#pragma unroll
  for (int t = 0; t < 12; t++) acc[t] = zero4;

  for (int kk = 0; kk < 4; kk++) {
    // stage x tile: 64 rows x 64 k (float4 -> bf16)
#pragma unroll
    for (int i = 0; i < 4; i++) {
      int idx = tid + i * 256;
      int row = idx >> 4;
      int c4 = (idx & 15) << 2;
      int n = n0 + row; if (n >= NROWS) n = NROWS - 1;
      float4 f = *(const float4*)(x + (size_t)n * 256 + kk * 64 + c4);
      u.s.As[row][c4 + 0] = f2bf(f.x);
      u.s.As[row][c4 + 1] = f2bf(f.y);
      u.s.As[row][c4 + 2] = f2bf(f.z);
      u.s.As[row][c4 + 3] = f2bf(f.w);
    }
    // stage W transposed: WsT[col][k] = W[k][col], 3 arrays of 64k x 64c
    {
      const float* Wptr[3] = { Wq, Wk, Wv };
#pragma unroll
      for (int a = 0; a < 3; a++) {
#pragma unroll
        for (int i = 0; i < 4; i++) {
          int idx = tid + i * 256;   // 1024 float4 units
          int k = idx >> 4;
          int c4 = (idx & 15) << 2;
          float4 f = *(const float4*)(Wptr[a] + ((size_t)h * 256 + kk * 64 + k) * 64 + c4);
          u.s.WsT[a * 64 + c4 + 0][k] = f2bf(f.x);
          u.s.WsT[a * 64 + c4 + 1][k] = f2bf(f.y);
          u.s.WsT[a * 64 + c4 + 2][k] = f2bf(f.z);
          u.s.WsT[a * 64 + c4 + 3][k] = f2bf(f.w);
        }
      }
    }
    __syncthreads();
    const int rw = wave * 16;
#pragma unroll
    for (int ks = 0; ks < 2; ks++) {
      s16x8 af = *(const s16x8*)&u.s.As[rw + (lane & 15)][ks * 32 + (lane >> 4) * 8];
#pragma unroll
      for (int t = 0; t < 12; t++) {
        s16x8 bfv = *(const s16x8*)&u.s.WsT[t * 16 + (lane & 15)][ks * 32 + (lane >> 4) * 8];
        acc[t] = __builtin_amdgcn_mfma_f32_16x16x32_bf16(af, bfv, acc[t], 0, 0, 0);
      }
    }
    __syncthreads();
  }

  // write acc -> C (+bias). D layout: col=lane&15, row=(lane>>4)*4+reg
  {
    const int rw = wave * 16;
    int col0 = lane & 15;
    int rg = (lane >> 4) * 4;
#pragma unroll
    for (int t = 0; t < 12; t++) {
      int col = t * 16 + col0;
      float b = bias[col];
#pragma unroll
      for (int r = 0; r < 4; r++)
        u.C[rw + rg + r][col] = acc[t][r] + b;
    }
  }
  __syncthreads();

  const float inv_denom = 1.0f / (fabsf(nsc[0]) + 1e-6f);

  // per-row norms for q and k (4 lanes/row, shfl reduce)
  {
    int row = tid >> 2;
    int part = tid & 3;
    float s2q = 0.f, s4q = 0.f, s2k = 0.f, s4k = 0.f;
#pragma unroll
    for (int i = 0; i < 16; i++) {
      int c = part * 16 + i;
      float q = u.C[row][c];
      float yq = (fmaxf(q, 0.f) + 1e-6f) * inv_denom;
      float yq2 = yq * yq;
      s2q += yq2; s4q += yq2 * yq2;
      float kv = u.C[row][64 + c];
      float yk = (fmaxf(kv, 0.f) + 1e-6f) * inv_denom;
      float yk2 = yk * yk;
      s2k += yk2; s4k += yk2 * yk2;
    }
    s2q += __shfl_xor(s2q, 1); s2q += __shfl_xor(s2q, 2);
    s4q += __shfl_xor(s4q, 1); s4q += __shfl_xor(s4q, 2);
    s2k += __shfl_xor(s2k, 1); s2k += __shfl_xor(s2k, 2);
    s4k += __shfl_xor(s4k, 1); s4k += __shfl_xor(s4k, 2);
    if (part == 0) {
      scl[row][0] = sqrtf(s2q) / (sqrtf(s4q) + 1e-12f);
      scl[row][1] = sqrtf(s2k) / (sqrtf(s4k) + 1e-12f);
    }
  }
  __syncthreads();

  // stores: phi_q, phi_k, v as bf16 ushort4
#pragma unroll
  for (int i = 0; i < 4; i++) {
    int idx = tid + i * 256;  // 1024 ushort4 units
    int row = idx >> 4;
    int c4 = (idx & 15) << 2;
    int n = n0 + row;
    if (n < NROWS) {
      size_t base = ((size_t)n * NH + h) * 64 + c4;
      float sq = scl[row][0], sk = scl[row][1];
      u16 pq[4], pk[4], pv[4];
#pragma unroll
      for (int j = 0; j < 4; j++) {
        float q = u.C[row][c4 + j];
        float yq = (fmaxf(q, 0.f) + 1e-6f) * inv_denom;
        pq[j] = f2bf(sq * yq * yq);
        float kv = u.C[row][64 + c4 + j];
        float yk = (fmaxf(kv, 0.f) + 1e-6f) * inv_denom;
        pk[j] = f2bf(sk * yk * yk);
        pv[j] = f2bf(u.C[row][128 + c4 + j]);
      }
      *(ushort4*)(phi_q + base) = make_ushort4(pq[0], pq[1], pq[2], pq[3]);
      *(ushort4*)(phi_k + base) = make_ushort4(pk[0], pk[1], pk[2], pk[3]);
      *(ushort4*)(vout + base) = make_ushort4(pv[0], pv[1], pv[2], pv[3]);
    }
  }
}

// ---------------------------------------------------------------------------
// Kernel 2: kT_v[h][m][d] = sum_n phi_k[n,h,m]*v[n,h,d]; sum_k[h][m].
// Per block: one head x 1024 rows, MFMA over 64-row subtiles, atomicAdd out.
// ---------------------------------------------------------------------------
__global__ __launch_bounds__(256) void k2_ktv(
    const u16* __restrict__ phi_k, const u16* __restrict__ vin,
    float* __restrict__ kTv, float* __restrict__ sumk)
{
  __shared__ u16 pkT[64][72];  // [m][row]
  __shared__ u16 vT[64][72];   // [d][row]
  const int tid = threadIdx.x;
  const int h = blockIdx.y;
  const int r0 = blockIdx.x * 1024;
  const int wave = tid >> 6;
  const int lane = tid & 63;

  f32x4 zero4 = {0.f, 0.f, 0.f, 0.f};
  f32x4 acc[4];
#pragma unroll
  for (int t = 0; t < 4; t++) acc[t] = zero4;
  float ssum = 0.f;

  for (int sub = 0; sub < 16; sub++) {
    int rbase = r0 + sub * 64;
#pragma unroll
    for (int i = 0; i < 4; i++) {
      int idx = tid + i * 256;
      int row = idx >> 4;
      int c4 = (idx & 15) << 2;
      int n = rbase + row;
      ushort4 pv = make_ushort4(0, 0, 0, 0), vv = make_ushort4(0, 0, 0, 0);
      if (n < NROWS) {
        size_t base = ((size_t)n * NH + h) * 64 + c4;
        pv = *(const ushort4*)(phi_k + base);
        vv = *(const ushort4*)(vin + base);
      }
      pkT[c4 + 0][row] = pv.x; pkT[c4 + 1][row] = pv.y;
      pkT[c4 + 2][row] = pv.z; pkT[c4 + 3][row] = pv.w;
      vT[c4 + 0][row] = vv.x; vT[c4 + 1][row] = vv.y;
      vT[c4 + 2][row] = vv.z; vT[c4 + 3][row] = vv.w;
    }
    __syncthreads();
    if (tid < 64) {
      const ushort4* p = (const ushort4*)&pkT[tid][0];
#pragma unroll
      for (int r4 = 0; r4 < 16; r4++) {
        ushort4 v4 = p[r4];
        ssum += bf2f(v4.x) + bf2f(v4.y) + bf2f(v4.z) + bf2f(v4.w);
      }
    }
#pragma unroll
    for (int ks = 0; ks < 2; ks++) {
      s16x8 af = *(const s16x8*)&pkT[wave * 16 + (lane & 15)][ks * 32 + (lane >> 4) * 8];
#pragma unroll
      for (int t = 0; t < 4; t++) {
        s16x8 bfv = *(const s16x8*)&vT[t * 16 + (lane & 15)][ks * 32 + (lane >> 4) * 8];
        acc[t] = __builtin_amdgcn_mfma_f32_16x16x32_bf16(af, bfv, acc[t], 0, 0, 0);
      }
    }
    __syncthreads();
  }
  {
    int m = wave * 16 + (lane >> 4) * 4;
    int d0 = lane & 15;
#pragma unroll
    for (int t = 0; t < 4; t++)
#pragma unroll
      for (int r = 0; r < 4; r++)
        atomicAdd(&kTv[((size_t)h * 64 + m + r) * 64 + t * 16 + d0], acc[t][r]);
  }
  if (tid < 64) atomicAdd(&sumk[h * 64 + tid], ssum);
}

// ---------------------------------------------------------------------------
// Kernel 2.5: pack kT_v^T (d-major) + sum_k (row 64) to bf16 [8][65][64]
// ---------------------------------------------------------------------------
__global__ __launch_bounds__(256) void k25_pack(
    const float* __restrict__ kTv, const float* __restrict__ sumk,
    u16* __restrict__ kTvT)
{
  int idx = blockIdx.x * 256 + threadIdx.x;
  if (idx >= NH * 65 * 64) return;
  int m = idx & 63;
  int rest = idx >> 6;
  int d = rest % 65;
  int h = rest / 65;
  float v = (d < 64) ? kTv[((size_t)h * 64 + m) * 64 + d] : sumk[h * 64 + m];
  kTvT[idx] = f2bf(v);
}

// ---------------------------------------------------------------------------
// Kernel 3: out[n] = mean_h( (phi_q@kTv[h]) / (phi_q.sum_k[h]+1e-6) )
//           + vbar@Wm + bm; lift to Lorentz. 64 rows/block, MFMA everywhere.
// ---------------------------------------------------------------------------
__global__ __launch_bounds__(256) void k3_out(
    const u16* __restrict__ phi_q, const u16* __restrict__ vin,
    const u16* __restrict__ kTvT,
    const float* __restrict__ Wm, const float* __restrict__ bm,
    float* __restrict__ out)
{
  __shared__ u16 B[NH][64][72];     // B[h][d][m] = kTv[h][m][d], 73728 B
  __shared__ u16 sumk_lds[NH][64];  // 1024 B
  __shared__ u16 WmT[64][72];       // WmT[d][e] = Wm[e][d]
  __shared__ u16 vbar[64][72];      // [row][e] mean_h v
  __shared__ float bml[64];

  const int tid = threadIdx.x;
  const int wave = tid >> 6;
  const int lane = tid & 63;
  const int n0 = blockIdx.x * 64;

  // stage kTvT + sumk (ushort4 units: 8*65*16 = 8320)
  for (int idx = tid; idx < NH * 65 * 16; idx += 256) {
    int m4 = (idx & 15) << 2;
    int rest = idx >> 4;
    int d = rest % 65;
    int h = rest / 65;
    ushort4 v4 = *(const ushort4*)(kTvT + ((size_t)(h * 65 + d) << 6) + m4);
    if (d < 64) *(ushort4*)&B[h][d][m4] = v4;
    else        *(ushort4*)&sumk_lds[h][m4] = v4;
  }
  // WmT
  for (int idx = tid; idx < 64 * 64; idx += 256) {
    int d = idx & 63;
    int e = idx >> 6;
    WmT[d][e] = f2bf(Wm[e * 64 + d]);
  }
  if (tid < 64) bml[tid] = bm[tid];
  // vbar = mean over heads of v
  for (int idx = tid; idx < 1024; idx += 256) {
    int row = idx >> 4;
    int c4 = (idx & 15) << 2;
    int n = n0 + row;
    float s0 = 0.f, s1 = 0.f, s2 = 0.f, s3 = 0.f;
    if (n < NROWS) {
      size_t base = (size_t)n * (NH * 64) + c4;
#pragma unroll
      for (int h = 0; h < NH; h++) {
        ushort4 v4 = *(const ushort4*)(vin + base + h * 64);
        s0 += bf2f(v4.x); s1 += bf2f(v4.y); s2 += bf2f(v4.z); s3 += bf2f(v4.w);
      }
    }
    vbar[row][c4 + 0] = f2bf(s0 * 0.125f);
    vbar[row][c4 + 1] = f2bf(s1 * 0.125f);
    vbar[row][c4 + 2] = f2bf(s2 * 0.125f);
    vbar[row][c4 + 3] = f2bf(s3 * 0.125f);
  }
  __syncthreads();

  const int rw = wave * 16;
  f32x4 zero4 = {0.f, 0.f, 0.f, 0.f};
  s16x8 zero8 = {0, 0, 0, 0, 0, 0, 0, 0};
  f32x4 osum[4];
#pragma unroll
  for (int t = 0; t < 4; t++) osum[t] = zero4;

  for (int h = 0; h < NH; h++) {
    f32x4 accn[4];
#pragma unroll
    for (int t = 0; t < 4; t++) accn[t] = zero4;
    f32x4 accd = zero4;
#pragma unroll
    for (int ks = 0; ks < 2; ks++) {
      int n = n0 + rw + (lane & 15);
      s16x8 af = zero8;
      if (n < NROWS)
        af = *(const s16x8*)(phi_q + ((size_t)n * NH + h) * 64 + ks * 32 + (lane >> 4) * 8);
#pragma unroll
      for (int t = 0; t < 4; t++) {
        s16x8 bfv = *(const s16x8*)&B[h][t * 16 + (lane & 15)][ks * 32 + (lane >> 4) * 8];
        accn[t] = __builtin_amdgcn_mfma_f32_16x16x32_bf16(af, bfv, accn[t], 0, 0, 0);
      }
      // denominator as an extra B-tile: only column n==0 nonzero (= sum_k)
      s16x8 bd = zero8;
      if ((lane & 15) == 0)
        bd = *(const s16x8*)&sumk_lds[h][ks * 32 + (lane >> 4) * 8];
      accd = __builtin_amdgcn_mfma_f32_16x16x32_bf16(af, bd, accd, 0, 0, 0);
    }
#pragma unroll
    for (int r = 0; r < 4; r++) {
      float den = __shfl(accd[r], lane & 48);  // broadcast from col-0 lane of row group
      float rinv = 1.0f / (den + 1e-6f);
#pragma unroll
      for (int t = 0; t < 4; t++) osum[t][r] += accn[t][r] * rinv;
    }
  }

  // residual vbar @ Wm
  f32x4 accr[4];
#pragma unroll
  for (int t = 0; t < 4; t++) accr[t] = zero4;
#pragma unroll
  for (int ks = 0; ks < 2; ks++) {
    s16x8 af = *(const s16x8*)&vbar[rw + (lane & 15)][ks * 32 + (lane >> 4) * 8];
#pragma unroll
    for (int t = 0; t < 4; t++) {
      s16x8 bfv = *(const s16x8*)&WmT[t * 16 + (lane & 15)][ks * 32 + (lane >> 4) * 8];
      accr[t] = __builtin_amdgcn_mfma_f32_16x16x32_bf16(af, bfv, accr[t], 0, 0, 0);
    }
  }

  // epilogue: combine, Lorentz lift, store [N,65]
  {
    int col0 = lane & 15;
    int rg = (lane >> 4) * 4;
#pragma unroll
    for (int r = 0; r < 4; r++) {
      int row = rw + rg + r;
      int n = n0 + row;
      float v4[4];
      float ssq = 0.f;
#pragma unroll
      for (int t = 0; t < 4; t++) {
        float o = osum[t][r] * 0.125f + accr[t][r] + bml[t * 16 + col0];
        v4[t] = o;
        ssq += o * o;
      }
      ssq += __shfl_xor(ssq, 1);
      ssq += __shfl_xor(ssq, 2);
      ssq += __shfl_xor(ssq, 4);
      ssq += __shfl_xor(ssq, 8);
      if (n < NROWS) {
        if (col0 == 0) out[(size_t)n * 65] = sqrtf(ssq + 1.0f);
#pragma unroll
        for (int t = 0; t < 4; t++)
          out[(size_t)n * 65 + 1 + t * 16 + col0] = v4[t];
      }
    }
  }
}

// ---------------------------------------------------------------------------
extern "C" void kernel_launch(void* const* d_in, const int* in_sizes, int n_in,
                              void* d_out, int out_size, void* d_ws, size_t ws_size,
                              hipStream_t stream) {
  const float* x   = (const float*)d_in[0];
  const float* Wq  = (const float*)d_in[1];
  const float* bq  = (const float*)d_in[2];
  const float* Wk  = (const float*)d_in[3];
  const float* bk  = (const float*)d_in[4];
  const float* Wv  = (const float*)d_in[5];
  const float* bv  = (const float*)d_in[6];
  const float* nsc = (const float*)d_in[7];
  const float* Wm  = (const float*)d_in[8];
  const float* bm  = (const float*)d_in[9];
  float* out = (float*)d_out;

  char* ws = (char*)d_ws;
  const size_t PHI_BYTES = (size_t)NROWS * NH * 64 * 2;  // 102,400,000
  u16* phi_q = (u16*)(ws);
  u16* phi_k = (u16*)(ws + PHI_BYTES);
  u16* vv    = (u16*)(ws + 2 * PHI_BYTES);
  float* kTv = (float*)(ws + 3 * PHI_BYTES);                        // [8][64][64] f32
  float* sumk = (float*)(ws + 3 * PHI_BYTES + 8 * 64 * 64 * 4);     // [8][64] f32
  u16* kTvT  = (u16*)(ws + 3 * PHI_BYTES + 8 * 64 * 64 * 4 + 8 * 64 * 4); // [8][65][64] bf16

  hipMemsetAsync(kTv, 0, 8 * 64 * 64 * 4 + 8 * 64 * 4, stream);

  dim3 g1((NROWS + 63) / 64, NH);
  k1_gemm_phi<<<g1, 256, 0, stream>>>(x, Wq, bq, Wk, bk, Wv, bv, nsc, phi_q, phi_k, vv);
  dim3 g2((NROWS + 1023) / 1024, NH);
  k2_ktv<<<g2, 256, 0, stream>>>(phi_k, vv, kTv, sumk);
  k25_pack<<<(NH * 65 * 64 + 255) / 256, 256, 0, stream>>>(kTv, sumk, kTvT);
  k3_out<<<(NROWS + 63) / 64, 256, 0, stream>>>(phi_q, vv, kTvT, Wm, bm, out);
}

// Round 2
// 793.468 us; speedup vs baseline: 1.6146x; 1.6146x over previous
//
#include <hip/hip_runtime.h>
#include <hip/hip_bf16.h>

#define NROWS 100000
#define NH 8

typedef short s16x8 __attribute__((ext_vector_type(8)));
typedef float f32x4 __attribute__((ext_vector_type(4)));
typedef unsigned short u16;

__device__ __forceinline__ u16 f2bf(float f) {
  union { float f; unsigned u; } x; x.f = f;
  unsigned r = (x.u + 0x7FFFu + ((x.u >> 16) & 1u)) >> 16;
  return (u16)r;
}
__device__ __forceinline__ float bf2f(u16 b) {
  union { unsigned u; float f; } x; x.u = ((unsigned)b) << 16;
  return x.f;
}

// ---------------------------------------------------------------------------
// Kernel 0: pack W (q|k|v, all heads) to bf16 in exact MFMA B-fragment order.
// Frag index t = ((hc*6 + tile)*8 + ks)*64 + lane, hc = h*2+c2.
// Column order per (h,c2):  c2=0: [q0..63, v0..31]   c2=1: [k0..63, v32..63]
// Value = W[h][k = ks*32 + (lane>>4)*8 + j][col],  8 u16 per frag-lane.
// ---------------------------------------------------------------------------
__global__ __launch_bounds__(256) void k0_pack(
    const float* __restrict__ Wq, const float* __restrict__ Wk,
    const float* __restrict__ Wv, u16* __restrict__ Wp)
{
  int t = blockIdx.x * 256 + threadIdx.x;   // 0..49151
  int lane = t & 63;
  int rest = t >> 6;                        // 0..767
  int ks = rest & 7; rest >>= 3;
  int tl = rest % 6;
  int hc = rest / 6;
  int c2 = hc & 1, h = hc >> 1;
  int m = lane & 15, sg = lane >> 4;
  int col_local = tl * 16 + m;
  const float* W; int col;
  if (col_local < 64) { W = c2 ? Wk : Wq; col = col_local; }
  else { W = Wv; col = (col_local - 64) + c2 * 32; }
  int k0 = ks * 32 + sg * 8;
  u16 o[8];
#pragma unroll
  for (int j = 0; j < 8; j++)
    o[j] = f2bf(W[((size_t)h * 256 + k0 + j) * 64 + col]);
  ushort4* dst = (ushort4*)(Wp + (size_t)t * 8);
  dst[0] = make_ushort4(o[0], o[1], o[2], o[3]);
  dst[1] = make_ushort4(o[4], o[5], o[6], o[7]);
}

// ---------------------------------------------------------------------------
// Kernel 1: 64 rows x all heads. x staged once (bf16, XOR-swizzled chunks).
// B-frags straight from global (L2-resident packed W). Waves: 2 row-halves
// x 2 col-halves; phi norms fully in-wave. sum_k accumulated here.
// Outputs phi_q/phi_k/v in [h][N][64] bf16.
// ---------------------------------------------------------------------------
__global__ __launch_bounds__(256, 2) void k1_gemm_phi(
    const float* __restrict__ x, const u16* __restrict__ Wp,
    const float* __restrict__ bq, const float* __restrict__ bk,
    const float* __restrict__ bv, const float* __restrict__ nsc,
    u16* __restrict__ phi_q, u16* __restrict__ phi_k, u16* __restrict__ vout,
    float* __restrict__ sumk)
{
  __shared__ u16 xs[64 * 256];        // addr = row*256 + (chunk ^ (row&7))*8
  __shared__ u16 st[64][204];         // store staging, stride 204 (conflict-free)
  __shared__ float bias[3 * 8 * 64];  // [a][h][col]

  const int tid = threadIdx.x;
  const int wv = tid >> 6, lane = tid & 63;
  const int r2 = wv >> 1, c2 = wv & 1;
  const int m = lane & 15, sg = lane >> 4;
  const int n0 = blockIdx.x * 64;

  for (int i = tid; i < 1536; i += 256) {
    int a = i >> 9, rest = i & 511;
    const float* bp = (a == 0) ? bq : (a == 1) ? bk : bv;
    bias[i] = bp[rest];
  }

  // stage x: fp32 -> bf16, swizzled 16B chunks
#pragma unroll
  for (int i = 0; i < 8; i++) {
    int unit = tid + i * 256;        // chunk 0..2047
    int row = unit >> 5;
    int c = unit & 31;
    int n = n0 + row; if (n >= NROWS) n = NROWS - 1;
    const float* src = x + (size_t)n * 256 + c * 8;
    float4 f0 = *(const float4*)src;
    float4 f1 = *(const float4*)(src + 4);
    u16* dst = xs + row * 256 + (c ^ (row & 7)) * 8;
    *(ushort4*)dst       = make_ushort4(f2bf(f0.x), f2bf(f0.y), f2bf(f0.z), f2bf(f0.w));
    *(ushort4*)(dst + 4) = make_ushort4(f2bf(f1.x), f2bf(f1.y), f2bf(f1.z), f2bf(f1.w));
  }
  __syncthreads();

  const float inv_denom = 1.0f / (fabsf(nsc[0]) + 1e-6f);
  const int row0 = r2 * 32 + m;
  const int row1 = row0 + 16;
  const int sw = m & 7;              // row0&7 == row1&7 == m&7

  for (int h = 0; h < NH; h++) {
    f32x4 acc[2][6];
#pragma unroll
    for (int rt = 0; rt < 2; rt++)
#pragma unroll
      for (int t = 0; t < 6; t++) acc[rt][t] = (f32x4){0.f, 0.f, 0.f, 0.f};

    const u16* wb = Wp + (size_t)(h * 2 + c2) * (6 * 8 * 64 * 8);
#pragma unroll
    for (int ks = 0; ks < 8; ks++) {
      int cch = ks * 4 + sg;
      s16x8 a0 = *(const s16x8*)(xs + row0 * 256 + (cch ^ sw) * 8);
      s16x8 a1 = *(const s16x8*)(xs + row1 * 256 + (cch ^ sw) * 8);
      s16x8 bfr[6];
#pragma unroll
      for (int t = 0; t < 6; t++)
        bfr[t] = *(const s16x8*)(wb + ((size_t)(t * 8 + ks) * 64 + lane) * 8);
#pragma unroll
      for (int t = 0; t < 6; t++) {
        acc[0][t] = __builtin_amdgcn_mfma_f32_16x16x32_bf16(a0, bfr[t], acc[0][t], 0, 0, 0);
        acc[1][t] = __builtin_amdgcn_mfma_f32_16x16x32_bf16(a1, bfr[t], acc[1][t], 0, 0, 0);
      }
    }

    // ---- epilogue (all in registers) ----
    float val[2][6][4];
#pragma unroll
    for (int t = 0; t < 6; t++) {
      int aidx, col;
      if (t < 4) { aidx = c2; col = t * 16 + m; }
      else { aidx = 2; col = c2 * 32 + (t - 4) * 16 + m; }
      float b = bias[aidx * 512 + h * 64 + col];
#pragma unroll
      for (int rt = 0; rt < 2; rt++)
#pragma unroll
        for (int r = 0; r < 4; r++)
          val[rt][t][r] = acc[rt][t][r] + b;
    }

    // phi on tiles 0..3 (q for c2=0, k for c2=1); per-row norms via shfl
#pragma unroll
    for (int rt = 0; rt < 2; rt++)
#pragma unroll
      for (int r = 0; r < 4; r++) {
        float s2 = 0.f, s4 = 0.f;
#pragma unroll
        for (int t = 0; t < 4; t++) {
          float y = (fmaxf(val[rt][t][r], 0.f) + 1e-6f) * inv_denom;
          float y2 = y * y;
          val[rt][t][r] = y2;
          s2 += y2; s4 += y2 * y2;
        }
        s2 += __shfl_xor(s2, 1); s2 += __shfl_xor(s2, 2);
        s2 += __shfl_xor(s2, 4); s2 += __shfl_xor(s2, 8);
        s4 += __shfl_xor(s4, 1); s4 += __shfl_xor(s4, 2);
        s4 += __shfl_xor(s4, 4); s4 += __shfl_xor(s4, 8);
        float sc = sqrtf(s2) / (sqrtf(s4) + 1e-12f);
#pragma unroll
        for (int t = 0; t < 4; t++) val[rt][t][r] *= sc;
      }

    // zero invalid rows (last block only) so sum_k stays correct
    if (n0 + 64 > NROWS) {
#pragma unroll
      for (int rt = 0; rt < 2; rt++)
#pragma unroll
        for (int r = 0; r < 4; r++)
          if (n0 + r2 * 32 + rt * 16 + sg * 4 + r >= NROWS) {
#pragma unroll
            for (int t = 0; t < 6; t++) val[rt][t][r] = 0.f;
          }
    }

    // sum_k over this block's rows (c2=1 waves hold phi_k)
    if (c2 == 1) {
#pragma unroll
      for (int t = 0; t < 4; t++) {
        float s = 0.f;
#pragma unroll
        for (int rt = 0; rt < 2; rt++)
#pragma unroll
          for (int r = 0; r < 4; r++) s += val[rt][t][r];
        s += __shfl_xor(s, 16);
        s += __shfl_xor(s, 32);
        if (lane < 16) atomicAdd(&sumk[h * 64 + t * 16 + m], s);
      }
    }

    // stage to st: cols [q(0..63) | k(64..127) | v(128..191)]
#pragma unroll
    for (int t = 0; t < 6; t++) {
      int colg = (t < 4) ? (c2 * 64 + t * 16 + m)
                         : (128 + c2 * 32 + (t - 4) * 16 + m);
#pragma unroll
      for (int rt = 0; rt < 2; rt++)
#pragma unroll
        for (int r = 0; r < 4; r++)
          st[r2 * 32 + rt * 16 + sg * 4 + r][colg] = f2bf(val[rt][t][r]);
    }
    __syncthreads();

    // coalesced flush: 3 arrays x 64 rows x 16 ushort4
    for (int u2 = tid; u2 < 3072; u2 += 256) {
      int a = u2 >> 10;
      int rr = (u2 >> 4) & 63;
      int c4 = (u2 & 15) << 2;
      int n = n0 + rr;
      if (n < NROWS) {
        u16* dstp = (a == 0) ? phi_q : (a == 1) ? phi_k : vout;
        ushort4 v4 = *(const ushort4*)&st[rr][a * 64 + c4];
        *(ushort4*)(dstp + (size_t)h * (NROWS * 64) + (size_t)n * 64 + c4) = v4;
      }
    }
    __syncthreads();
  }
}

// ---------------------------------------------------------------------------
// Kernel 2: kT_v[h][m][d] = sum_n phi_k[n][m] * v[n][d].  [h][N][64] inputs.
// Transpose staging: 64 lanes write 64 different rows -> conflict-free.
// ---------------------------------------------------------------------------
__global__ __launch_bounds__(256) void k2_ktv(
    const u16* __restrict__ phi_k, const u16* __restrict__ vin,
    float* __restrict__ kTv)
{
  __shared__ u16 pkT[64][72];  // [m][row]
  __shared__ u16 vT[64][72];   // [d][row]
  const int tid = threadIdx.x;
  const int h = blockIdx.y;
  const int r0 = blockIdx.x * 1024;
  const int wv = tid >> 6, lane = tid & 63;
  const int m = lane & 15, sg = lane >> 4;

  f32x4 acc[4];
#pragma unroll
  for (int t = 0; t < 4; t++) acc[t] = (f32x4){0.f, 0.f, 0.f, 0.f};

  const u16* pkb = phi_k + (size_t)h * (NROWS * 64);
  const u16* vb  = vin  + (size_t)h * (NROWS * 64);

  for (int sub = 0; sub < 16; sub++) {
    int rbase = r0 + sub * 64;
#pragma unroll
    for (int i = 0; i < 4; i++) {
      int idx = tid + i * 256;       // 0..1023
      int row = idx & 63;            // lanes cover 64 distinct rows
      int c4 = (idx >> 6) << 2;
      int n = rbase + row;
      ushort4 pv = make_ushort4(0, 0, 0, 0), vv4 = make_ushort4(0, 0, 0, 0);
      if (n < NROWS) {
        pv  = *(const ushort4*)(pkb + (size_t)n * 64 + c4);
        vv4 = *(const ushort4*)(vb  + (size_t)n * 64 + c4);
      }
      pkT[c4 + 0][row] = pv.x;  pkT[c4 + 1][row] = pv.y;
      pkT[c4 + 2][row] = pv.z;  pkT[c4 + 3][row] = pv.w;
      vT[c4 + 0][row] = vv4.x;  vT[c4 + 1][row] = vv4.y;
      vT[c4 + 2][row] = vv4.z;  vT[c4 + 3][row] = vv4.w;
    }
    __syncthreads();
#pragma unroll
    for (int ks = 0; ks < 2; ks++) {
      s16x8 af = *(const s16x8*)&pkT[wv * 16 + m][ks * 32 + sg * 8];
#pragma unroll
      for (int t = 0; t < 4; t++) {
        s16x8 bfv = *(const s16x8*)&vT[t * 16 + m][ks * 32 + sg * 8];
        acc[t] = __builtin_amdgcn_mfma_f32_16x16x32_bf16(af, bfv, acc[t], 0, 0, 0);
      }
    }
    __syncthreads();
  }
  {
    int mm = wv * 16 + sg * 4;
#pragma unroll
    for (int t = 0; t < 4; t++)
#pragma unroll
      for (int r = 0; r < 4; r++)
        atomicAdd(&kTv[((size_t)h * 64 + mm + r) * 64 + t * 16 + m], acc[t][r]);
  }
}

// ---------------------------------------------------------------------------
// Kernel 2.5: pack kT_v^T (d-major) + sum_k (row 64) to bf16 [8][65][64]
// ---------------------------------------------------------------------------
__global__ __launch_bounds__(256) void k25_pack(
    const float* __restrict__ kTv, const float* __restrict__ sumk,
    u16* __restrict__ kTvT)
{
  int idx = blockIdx.x * 256 + threadIdx.x;
  if (idx >= NH * 65 * 64) return;
  int m = idx & 63;
  int rest = idx >> 6;
  int d = rest % 65;
  int h = rest / 65;
  float v = (d < 64) ? kTv[((size_t)h * 64 + m) * 64 + d] : sumk[h * 64 + m];
  kTvT[idx] = f2bf(v);
}

// ---------------------------------------------------------------------------
// Kernel 3: out = mean_h( (phi_q@kTv[h]) / (phi_q.sum_k[h]+1e-6) )
//           + vbar@Wm + bm; Lorentz lift. Inputs [h][N][64].
// ---------------------------------------------------------------------------
__global__ __launch_bounds__(256) void k3_out(
    const u16* __restrict__ phi_q, const u16* __restrict__ vin,
    const u16* __restrict__ kTvT,
    const float* __restrict__ Wm, const float* __restrict__ bm,
    float* __restrict__ out)
{
  __shared__ u16 B[NH][64][72];
  __shared__ u16 sumk_lds[NH][64];
  __shared__ u16 WmT[64][72];
  __shared__ u16 vbar[64][72];
  __shared__ float bml[64];

  const int tid = threadIdx.x;
  const int wave = tid >> 6;
  const int lane = tid & 63;
  const int n0 = blockIdx.x * 64;

  for (int idx = tid; idx < NH * 65 * 16; idx += 256) {
    int m4 = (idx & 15) << 2;
    int rest = idx >> 4;
    int d = rest % 65;
    int h = rest / 65;
    ushort4 v4 = *(const ushort4*)(kTvT + ((size_t)(h * 65 + d) << 6) + m4);
    if (d < 64) *(ushort4*)&B[h][d][m4] = v4;
    else        *(ushort4*)&sumk_lds[h][m4] = v4;
  }
  for (int idx = tid; idx < 64 * 64; idx += 256) {
    int d = idx & 63;
    int e = idx >> 6;
    WmT[d][e] = f2bf(Wm[e * 64 + d]);
  }
  if (tid < 64) bml[tid] = bm[tid];
  for (int idx = tid; idx < 1024; idx += 256) {
    int row = idx >> 4;
    int c4 = (idx & 15) << 2;
    int n = n0 + row;
    float s0 = 0.f, s1 = 0.f, s2 = 0.f, s3 = 0.f;
    if (n < NROWS) {
#pragma unroll
      for (int h = 0; h < NH; h++) {
        ushort4 v4 = *(const ushort4*)(vin + (size_t)h * (NROWS * 64) + (size_t)n * 64 + c4);
        s0 += bf2f(v4.x); s1 += bf2f(v4.y); s2 += bf2f(v4.z); s3 += bf2f(v4.w);
      }
    }
    vbar[row][c4 + 0] = f2bf(s0 * 0.125f);
    vbar[row][c4 + 1] = f2bf(s1 * 0.125f);
    vbar[row][c4 + 2] = f2bf(s2 * 0.125f);
    vbar[row][c4 + 3] = f2bf(s3 * 0.125f);
  }
  __syncthreads();

  const int rw = wave * 16;
  f32x4 zero4 = {0.f, 0.f, 0.f, 0.f};
  s16x8 zero8 = {0, 0, 0, 0, 0, 0, 0, 0};
  f32x4 osum[4];
#pragma unroll
  for (int t = 0; t < 4; t++) osum[t] = zero4;

  for (int h = 0; h < NH; h++) {
    f32x4 accn[4];
#pragma unroll
    for (int t = 0; t < 4; t++) accn[t] = zero4;
    f32x4 accd = zero4;
#pragma unroll
    for (int ks = 0; ks < 2; ks++) {
      int n = n0 + rw + (lane & 15);
      s16x8 af = zero8;
      if (n < NROWS)
        af = *(const s16x8*)(phi_q + (size_t)h * (NROWS * 64) + (size_t)n * 64
                             + ks * 32 + (lane >> 4) * 8);
#pragma unroll
      for (int t = 0; t < 4; t++) {
        s16x8 bfv = *(const s16x8*)&B[h][t * 16 + (lane & 15)][ks * 32 + (lane >> 4) * 8];
        accn[t] = __builtin_amdgcn_mfma_f32_16x16x32_bf16(af, bfv, accn[t], 0, 0, 0);
      }
      s16x8 bd = zero8;
      if ((lane & 15) == 0)
        bd = *(const s16x8*)&sumk_lds[h][ks * 32 + (lane >> 4) * 8];
      accd = __builtin_amdgcn_mfma_f32_16x16x32_bf16(af, bd, accd, 0, 0, 0);
    }
#pragma unroll
    for (int r = 0; r < 4; r++) {
      float den = __shfl(accd[r], lane & 48);
      float rinv = 1.0f / (den + 1e-6f);
#pragma unroll
      for (int t = 0; t < 4; t++) osum[t][r] += accn[t][r] * rinv;
    }
  }

  f32x4 accr[4];
#pragma unroll
  for (int t = 0; t < 4; t++) accr[t] = zero4;
#pragma unroll
  for (int ks = 0; ks < 2; ks++) {
    s16x8 af = *(const s16x8*)&vbar[rw + (lane & 15)][ks * 32 + (lane >> 4) * 8];
#pragma unroll
    for (int t = 0; t < 4; t++) {
      s16x8 bfv = *(const s16x8*)&WmT[t * 16 + (lane & 15)][ks * 32 + (lane >> 4) * 8];
      accr[t] = __builtin_amdgcn_mfma_f32_16x16x32_bf16(af, bfv, accr[t], 0, 0, 0);
    }
  }

  {
    int col0 = lane & 15;
    int rg = (lane >> 4) * 4;
#pragma unroll
    for (int r = 0; r < 4; r++) {
      int row = rw + rg + r;
      int n = n0 + row;
      float v4[4];
      float ssq = 0.f;
#pragma unroll
      for (int t = 0; t < 4; t++) {
        float o = osum[t][r] * 0.125f + accr[t][r] + bml[t * 16 + col0];
        v4[t] = o;
        ssq += o * o;
      }
      ssq += __shfl_xor(ssq, 1);
      ssq += __shfl_xor(ssq, 2);
      ssq += __shfl_xor(ssq, 4);
      ssq += __shfl_xor(ssq, 8);
      if (n < NROWS) {
        if (col0 == 0) out[(size_t)n * 65] = sqrtf(ssq + 1.0f);
#pragma unroll
        for (int t = 0; t < 4; t++)
          out[(size_t)n * 65 + 1 + t * 16 + col0] = v4[t];
      }
    }
  }
}

// ---------------------------------------------------------------------------
extern "C" void kernel_launch(void* const* d_in, const int* in_sizes, int n_in,
                              void* d_out, int out_size, void* d_ws, size_t ws_size,
                              hipStream_t stream) {
  const float* x   = (const float*)d_in[0];
  const float* Wq  = (const float*)d_in[1];
  const float* bq  = (const float*)d_in[2];
  const float* Wk  = (const float*)d_in[3];
  const float* bk  = (const float*)d_in[4];
  const float* Wv  = (const float*)d_in[5];
  const float* bv  = (const float*)d_in[6];
  const float* nsc = (const float*)d_in[7];
  const float* Wm  = (const float*)d_in[8];
  const float* bm  = (const float*)d_in[9];
  float* out = (float*)d_out;

  char* ws = (char*)d_ws;
  const size_t PHI_BYTES = (size_t)NROWS * NH * 64 * 2;   // 102,400,000
  u16* phi_q = (u16*)(ws);
  u16* phi_k = (u16*)(ws + PHI_BYTES);
  u16* vv    = (u16*)(ws + 2 * PHI_BYTES);
  u16* Wp    = (u16*)(ws + 3 * PHI_BYTES);                // 49152*8 u16 = 786,432 B
  char* p    = ws + 3 * PHI_BYTES + 786432;
  float* kTv  = (float*)(p);                              // 131,072 B
  float* sumk = (float*)(p + 131072);                     // 2,048 B
  u16*  kTvT  = (u16*)(p + 131072 + 2048);                // 66,560 B

  hipMemsetAsync(kTv, 0, 131072 + 2048, stream);

  k0_pack<<<192, 256, 0, stream>>>(Wq, Wk, Wv, Wp);
  dim3 g1((NROWS + 63) / 64);
  k1_gemm_phi<<<g1, 256, 0, stream>>>(x, Wp, bq, bk, bv, nsc, phi_q, phi_k, vv, sumk);
  dim3 g2((NROWS + 1023) / 1024, NH);
  k2_ktv<<<g2, 256, 0, stream>>>(phi_k, vv, kTv);
  k25_pack<<<(NH * 65 * 64 + 255) / 256, 256, 0, stream>>>(kTv, sumk, kTvT);
  k3_out<<<(NROWS + 63) / 64, 256, 0, stream>>>(phi_q, vv, kTvT, Wm, bm, out);
}

// Round 3
// 715.081 us; speedup vs baseline: 1.7915x; 1.1096x over previous
//
#include <hip/hip_runtime.h>
#include <hip/hip_bf16.h>

#define NROWS 100000
#define NH 8

typedef short s16x8 __attribute__((ext_vector_type(8)));
typedef float f32x4 __attribute__((ext_vector_type(4)));
typedef unsigned short u16;

__device__ __forceinline__ u16 f2bf(float f) {
  union { float f; unsigned u; } x; x.f = f;
  unsigned r = (x.u + 0x7FFFu + ((x.u >> 16) & 1u)) >> 16;
  return (u16)r;
}
__device__ __forceinline__ float bf2f(u16 b) {
  union { unsigned u; float f; } x; x.u = ((unsigned)b) << 16;
  return x.f;
}

// ---------------------------------------------------------------------------
// Kernel 0: pack W (q|k|v, all heads) to bf16 in MFMA fragment order.
// Frag index t = ((hc*6 + tile)*8 + ks)*64 + lane, hc = h*2+c2.
// Used as the A-operand: A[i=col][k] = W[k][col].
// ---------------------------------------------------------------------------
__global__ __launch_bounds__(256) void k0_pack(
    const float* __restrict__ Wq, const float* __restrict__ Wk,
    const float* __restrict__ Wv, u16* __restrict__ Wp)
{
  int t = blockIdx.x * 256 + threadIdx.x;   // 0..49151
  int lane = t & 63;
  int rest = t >> 6;
  int ks = rest & 7; rest >>= 3;
  int tl = rest % 6;
  int hc = rest / 6;
  int c2 = hc & 1, h = hc >> 1;
  int m = lane & 15, sg = lane >> 4;
  int col_local = tl * 16 + m;
  const float* W; int col;
  if (col_local < 64) { W = c2 ? Wk : Wq; col = col_local; }
  else { W = Wv; col = (col_local - 64) + c2 * 32; }
  int k0 = ks * 32 + sg * 8;
  u16 o[8];
#pragma unroll
  for (int j = 0; j < 8; j++)
    o[j] = f2bf(W[((size_t)h * 256 + k0 + j) * 64 + col]);
  ushort4* dst = (ushort4*)(Wp + (size_t)t * 8);
  dst[0] = make_ushort4(o[0], o[1], o[2], o[3]);
  dst[1] = make_ushort4(o[4], o[5], o[6], o[7]);
}

// ---------------------------------------------------------------------------
// Kernel 1: 64 rows x all heads, operand-swapped MFMA (A=W, B=x) so D is
// channel-major per lane -> direct ushort4 global stores, no store staging,
// no barriers in the head loop. Outputs phi_q/phi_k/v in [h][N][64] bf16.
// ---------------------------------------------------------------------------
__global__ __launch_bounds__(256, 4) void k1_gemm_phi(
    const float* __restrict__ x, const u16* __restrict__ Wp,
    const float* __restrict__ bq, const float* __restrict__ bk,
    const float* __restrict__ bv, const float* __restrict__ nsc,
    u16* __restrict__ phi_q, u16* __restrict__ phi_k, u16* __restrict__ vout)
{
  __shared__ u16 xs[64 * 256];        // addr = row*256 + (chunk ^ (row&7))*8
  __shared__ float bias[3 * 8 * 64];  // [a][h][col]

  const int tid = threadIdx.x;
  const int wv = tid >> 6, lane = tid & 63;
  const int r2 = wv >> 1, c2 = wv & 1;
  const int m = lane & 15, sg = lane >> 4;
  const int n0 = blockIdx.x * 64;

  for (int i = tid; i < 1536; i += 256) {
    int a = i >> 9, rest = i & 511;
    const float* bp = (a == 0) ? bq : (a == 1) ? bk : bv;
    bias[i] = bp[rest];
  }

  // stage x: fp32 -> bf16, XOR-swizzled 16B chunks
#pragma unroll
  for (int i = 0; i < 8; i++) {
    int unit = tid + i * 256;        // chunk 0..2047
    int row = unit >> 5;
    int c = unit & 31;
    int n = n0 + row; if (n >= NROWS) n = NROWS - 1;
    const float* src = x + (size_t)n * 256 + c * 8;
    float4 f0 = *(const float4*)src;
    float4 f1 = *(const float4*)(src + 4);
    u16* dst = xs + row * 256 + (c ^ (row & 7)) * 8;
    *(ushort4*)dst       = make_ushort4(f2bf(f0.x), f2bf(f0.y), f2bf(f0.z), f2bf(f0.w));
    *(ushort4*)(dst + 4) = make_ushort4(f2bf(f1.x), f2bf(f1.y), f2bf(f1.z), f2bf(f1.w));
  }
  __syncthreads();

  const float inv_denom = 1.0f / (fabsf(nsc[0]) + 1e-6f);
  const int row0 = r2 * 32 + m;
  const int row1 = row0 + 16;
  const int sw = m & 7;

  for (int h = 0; h < NH; h++) {
    f32x4 acc[2][6];
#pragma unroll
    for (int rt = 0; rt < 2; rt++)
#pragma unroll
      for (int t = 0; t < 6; t++) acc[rt][t] = (f32x4){0.f, 0.f, 0.f, 0.f};

    const u16* wb = Wp + (size_t)(h * 2 + c2) * (6 * 8 * 64 * 8);
#pragma unroll
    for (int ks = 0; ks < 8; ks++) {
      int cch = ks * 4 + sg;
      s16x8 b0 = *(const s16x8*)(xs + row0 * 256 + (cch ^ sw) * 8);
      s16x8 b1 = *(const s16x8*)(xs + row1 * 256 + (cch ^ sw) * 8);
      s16x8 wfr[6];
#pragma unroll
      for (int t = 0; t < 6; t++)
        wfr[t] = *(const s16x8*)(wb + ((size_t)(t * 8 + ks) * 64 + lane) * 8);
#pragma unroll
      for (int t = 0; t < 6; t++) {
        acc[0][t] = __builtin_amdgcn_mfma_f32_16x16x32_bf16(wfr[t], b0, acc[0][t], 0, 0, 0);
        acc[1][t] = __builtin_amdgcn_mfma_f32_16x16x32_bf16(wfr[t], b1, acc[1][t], 0, 0, 0);
      }
    }

    // bias fragments (channel c = t*16 + sg*4 + r)
    f32x4 bfrag[6];
#pragma unroll
    for (int t = 0; t < 4; t++)
      bfrag[t] = *(const f32x4*)&bias[c2 * 512 + h * 64 + t * 16 + sg * 4];
#pragma unroll
    for (int tv = 0; tv < 2; tv++)
      bfrag[4 + tv] = *(const f32x4*)&bias[2 * 512 + h * 64 + c2 * 32 + tv * 16 + sg * 4];

#pragma unroll
    for (int rt = 0; rt < 2; rt++) {
      int n = n0 + r2 * 32 + rt * 16 + m;
      float vq[4][4];
      float s2 = 0.f, s4 = 0.f;
#pragma unroll
      for (int t = 0; t < 4; t++)
#pragma unroll
        for (int r = 0; r < 4; r++) {
          float y = (fmaxf(acc[rt][t][r] + bfrag[t][r], 0.f) + 1e-6f) * inv_denom;
          float y2 = y * y;
          vq[t][r] = y2;
          s2 += y2; s4 += y2 * y2;
        }
      s2 += __shfl_xor(s2, 16); s2 += __shfl_xor(s2, 32);
      s4 += __shfl_xor(s4, 16); s4 += __shfl_xor(s4, 32);
      float sc = sqrtf(s2) / (sqrtf(s4) + 1e-12f);
      if (n < NROWS) {
        u16* pb = (c2 ? phi_k : phi_q) + (size_t)h * (NROWS * 64) + (size_t)n * 64;
#pragma unroll
        for (int t = 0; t < 4; t++)
          *(ushort4*)(pb + t * 16 + sg * 4) =
            make_ushort4(f2bf(vq[t][0] * sc), f2bf(vq[t][1] * sc),
                         f2bf(vq[t][2] * sc), f2bf(vq[t][3] * sc));
        u16* vb = vout + (size_t)h * (NROWS * 64) + (size_t)n * 64 + c2 * 32;
#pragma unroll
        for (int tv = 0; tv < 2; tv++) {
          f32x4 a = acc[rt][4 + tv];
          f32x4 b = bfrag[4 + tv];
          *(ushort4*)(vb + tv * 16 + sg * 4) =
            make_ushort4(f2bf(a[0] + b[0]), f2bf(a[1] + b[1]),
                         f2bf(a[2] + b[2]), f2bf(a[3] + b[3]));
        }
      }
    }
  }
}

// ---------------------------------------------------------------------------
// Kernel 2: kT_v[h][m][d] = sum_n phi_k[n][m] * v[n][d]; sum_k via a
// ones-column MFMA. Transpose staging is conflict-free on the write side.
// ---------------------------------------------------------------------------
__global__ __launch_bounds__(256) void k2_ktv(
    const u16* __restrict__ phi_k, const u16* __restrict__ vin,
    float* __restrict__ kTv, float* __restrict__ sumk)
{
  __shared__ u16 pkT[64][72];  // [m][row]
  __shared__ u16 vT[64][72];   // [d][row]
  const int tid = threadIdx.x;
  const int h = blockIdx.y;
  const int r0 = blockIdx.x * 1024;
  const int wv = tid >> 6, lane = tid & 63;
  const int m = lane & 15, sg = lane >> 4;

  f32x4 acc[4];
#pragma unroll
  for (int t = 0; t < 4; t++) acc[t] = (f32x4){0.f, 0.f, 0.f, 0.f};
  f32x4 accs = (f32x4){0.f, 0.f, 0.f, 0.f};
  s16x8 onesf;
#pragma unroll
  for (int j = 0; j < 8; j++) onesf[j] = (m == 0) ? (short)0x3F80 : (short)0;

  const u16* pkb = phi_k + (size_t)h * (NROWS * 64);
  const u16* vb  = vin  + (size_t)h * (NROWS * 64);

  for (int sub = 0; sub < 16; sub++) {
    int rbase = r0 + sub * 64;
#pragma unroll
    for (int i = 0; i < 4; i++) {
      int idx = tid + i * 256;
      int row = idx & 63;            // lanes cover 64 distinct rows
      int c4 = (idx >> 6) << 2;
      int n = rbase + row;
      ushort4 pv = make_ushort4(0, 0, 0, 0), vv4 = make_ushort4(0, 0, 0, 0);
      if (n < NROWS) {
        pv  = *(const ushort4*)(pkb + (size_t)n * 64 + c4);
        vv4 = *(const ushort4*)(vb  + (size_t)n * 64 + c4);
      }
      pkT[c4 + 0][row] = pv.x;  pkT[c4 + 1][row] = pv.y;
      pkT[c4 + 2][row] = pv.z;  pkT[c4 + 3][row] = pv.w;
      vT[c4 + 0][row] = vv4.x;  vT[c4 + 1][row] = vv4.y;
      vT[c4 + 2][row] = vv4.z;  vT[c4 + 3][row] = vv4.w;
    }
    __syncthreads();
#pragma unroll
    for (int ks = 0; ks < 2; ks++) {
      s16x8 af = *(const s16x8*)&pkT[wv * 16 + m][ks * 32 + sg * 8];
#pragma unroll
      for (int t = 0; t < 4; t++) {
        s16x8 bfv = *(const s16x8*)&vT[t * 16 + m][ks * 32 + sg * 8];
        acc[t] = __builtin_amdgcn_mfma_f32_16x16x32_bf16(af, bfv, acc[t], 0, 0, 0);
      }
      accs = __builtin_amdgcn_mfma_f32_16x16x32_bf16(af, onesf, accs, 0, 0, 0);
    }
    __syncthreads();
  }
  {
    int mm = wv * 16 + sg * 4;
#pragma unroll
    for (int t = 0; t < 4; t++)
#pragma unroll
      for (int r = 0; r < 4; r++)
        atomicAdd(&kTv[((size_t)h * 64 + mm + r) * 64 + t * 16 + m], acc[t][r]);
    if (m == 0)
#pragma unroll
      for (int r = 0; r < 4; r++)
        atomicAdd(&sumk[h * 64 + mm + r], accs[r]);
  }
}

// ---------------------------------------------------------------------------
// Kernel 2.5: pack kT_v^T (d-major, +sumk as row 64) -> bf16 [8][65][64],
// and WmP[e][d] = Wm[d][e] -> bf16 (B-fragment-friendly).
// ---------------------------------------------------------------------------
__global__ __launch_bounds__(256) void k25_pack(
    const float* __restrict__ kTv, const float* __restrict__ sumk,
    const float* __restrict__ Wm,
    u16* __restrict__ kTvT, u16* __restrict__ WmP)
{
  int idx = blockIdx.x * 256 + threadIdx.x;
  if (idx < NH * 65 * 64) {
    int m = idx & 63;
    int rest = idx >> 6;
    int d = rest % 65;
    int h = rest / 65;
    float v = (d < 64) ? kTv[((size_t)h * 64 + m) * 64 + d] : sumk[h * 64 + m];
    kTvT[idx] = f2bf(v);
  } else if (idx < NH * 65 * 64 + 64 * 64) {
    int j = idx - NH * 65 * 64;
    int e = j >> 6, d = j & 63;
    WmP[j] = f2bf(Wm[d * 64 + e]);
  }
}

// ---------------------------------------------------------------------------
// Kernel 3: out = mean_h( (phi_q@kTv[h]) / (phi_q.sum_k[h]+1e-6) )
//           + vbar@Wm + bm; Lorentz lift. ZERO LDS, zero barriers.
// All small operands (kTvT, WmP, bm) read straight from global/L2.
// ---------------------------------------------------------------------------
__global__ __launch_bounds__(256) void k3_out(
    const u16* __restrict__ phi_q, const u16* __restrict__ vin,
    const u16* __restrict__ kTvT, const u16* __restrict__ WmP,
    const float* __restrict__ bm, float* __restrict__ out)
{
  const int tid = threadIdx.x;
  const int wv = tid >> 6, lane = tid & 63;
  const int m = lane & 15, sg = lane >> 4;
  const int n0 = blockIdx.x * 64;
  const int rw = wv * 16;
  const int n = n0 + rw + m;     // row carried by this lane's A-fragments

  float bmv[4];
#pragma unroll
  for (int t = 0; t < 4; t++) bmv[t] = bm[t * 16 + m];

  // vbar fragments (A-layout): average v over heads, in registers
  s16x8 vbf[2];
#pragma unroll
  for (int ks = 0; ks < 2; ks++) {
    float a[8];
#pragma unroll
    for (int j = 0; j < 8; j++) a[j] = 0.f;
#pragma unroll
    for (int h = 0; h < NH; h++) {
      s16x8 v8 = *(const s16x8*)(vin + (size_t)h * (NROWS * 64) + (size_t)n * 64
                                 + ks * 32 + sg * 8);
#pragma unroll
      for (int j = 0; j < 8; j++) a[j] += bf2f((u16)v8[j]);
    }
#pragma unroll
    for (int j = 0; j < 8; j++) vbf[ks][j] = (short)f2bf(a[j] * 0.125f);
  }

  f32x4 zero4 = {0.f, 0.f, 0.f, 0.f};
  s16x8 zero8 = {0, 0, 0, 0, 0, 0, 0, 0};
  f32x4 osum[4];
#pragma unroll
  for (int t = 0; t < 4; t++) osum[t] = zero4;

  for (int h = 0; h < NH; h++) {
    const u16* pqb = phi_q + (size_t)h * (NROWS * 64) + (size_t)n * 64;
    const u16* kb = kTvT + (size_t)h * (65 * 64);
    f32x4 accn[4];
#pragma unroll
    for (int t = 0; t < 4; t++) accn[t] = zero4;
    f32x4 accd = zero4;
#pragma unroll
    for (int ks = 0; ks < 2; ks++) {
      s16x8 aq = *(const s16x8*)(pqb + ks * 32 + sg * 8);
#pragma unroll
      for (int t = 0; t < 4; t++) {
        s16x8 bfv = *(const s16x8*)(kb + (size_t)(t * 16 + m) * 64 + ks * 32 + sg * 8);
        accn[t] = __builtin_amdgcn_mfma_f32_16x16x32_bf16(aq, bfv, accn[t], 0, 0, 0);
      }
      s16x8 bd = zero8;
      if (m == 0)
        bd = *(const s16x8*)(kb + (size_t)64 * 64 + ks * 32 + sg * 8);
      accd = __builtin_amdgcn_mfma_f32_16x16x32_bf16(aq, bd, accd, 0, 0, 0);
    }
#pragma unroll
    for (int r = 0; r < 4; r++) {
      float den = __shfl(accd[r], lane & 48);
      float rinv = 1.0f / (den + 1e-6f);
#pragma unroll
      for (int t = 0; t < 4; t++) osum[t][r] += accn[t][r] * rinv;
    }
  }

  // residual vbar @ Wm
  f32x4 accr[4];
#pragma unroll
  for (int t = 0; t < 4; t++) accr[t] = zero4;
#pragma unroll
  for (int ks = 0; ks < 2; ks++)
#pragma unroll
    for (int t = 0; t < 4; t++) {
      s16x8 bw = *(const s16x8*)(WmP + (size_t)(t * 16 + m) * 64 + ks * 32 + sg * 8);
      accr[t] = __builtin_amdgcn_mfma_f32_16x16x32_bf16(vbf[ks], bw, accr[t], 0, 0, 0);
    }

  // epilogue: combine, Lorentz lift, store [N,65]
#pragma unroll
  for (int r = 0; r < 4; r++) {
    int nn = n0 + rw + sg * 4 + r;
    float v4[4];
    float ssq = 0.f;
#pragma unroll
    for (int t = 0; t < 4; t++) {
      float o = osum[t][r] * 0.125f + accr[t][r] + bmv[t];
      v4[t] = o;
      ssq += o * o;
    }
    ssq += __shfl_xor(ssq, 1);
    ssq += __shfl_xor(ssq, 2);
    ssq += __shfl_xor(ssq, 4);
    ssq += __shfl_xor(ssq, 8);
    if (nn < NROWS) {
      if (m == 0) out[(size_t)nn * 65] = sqrtf(ssq + 1.0f);
#pragma unroll
      for (int t = 0; t < 4; t++)
        out[(size_t)nn * 65 + 1 + t * 16 + m] = v4[t];
    }
  }
}

// ---------------------------------------------------------------------------
extern "C" void kernel_launch(void* const* d_in, const int* in_sizes, int n_in,
                              void* d_out, int out_size, void* d_ws, size_t ws_size,
                              hipStream_t stream) {
  const float* x   = (const float*)d_in[0];
  const float* Wq  = (const float*)d_in[1];
  const float* bq  = (const float*)d_in[2];
  const float* Wk  = (const float*)d_in[3];
  const float* bk  = (const float*)d_in[4];
  const float* Wv  = (const float*)d_in[5];
  const float* bv  = (const float*)d_in[6];
  const float* nsc = (const float*)d_in[7];
  const float* Wm  = (const float*)d_in[8];
  const float* bm  = (const float*)d_in[9];
  float* out = (float*)d_out;

  char* ws = (char*)d_ws;
  const size_t PHI_BYTES = (size_t)NROWS * NH * 64 * 2;   // 102,400,000
  u16* phi_q = (u16*)(ws);
  u16* phi_k = (u16*)(ws + PHI_BYTES);
  u16* vv    = (u16*)(ws + 2 * PHI_BYTES);
  u16* Wp    = (u16*)(ws + 3 * PHI_BYTES);                // 786,432 B
  char* p    = ws + 3 * PHI_BYTES + 786432;
  float* kTv  = (float*)(p);                              // 131,072 B
  float* sumk = (float*)(p + 131072);                     // 2,048 B
  u16*  kTvT  = (u16*)(p + 131072 + 2048);                // 66,560 B
  u16*  WmP   = (u16*)(p + 131072 + 2048 + 66560);        // 8,192 B

  hipMemsetAsync(kTv, 0, 131072 + 2048, stream);

  k0_pack<<<192, 256, 0, stream>>>(Wq, Wk, Wv, Wp);
  dim3 g1((NROWS + 63) / 64);
  k1_gemm_phi<<<g1, 256, 0, stream>>>(x, Wp, bq, bk, bv, nsc, phi_q, phi_k, vv);
  dim3 g2((NROWS + 1023) / 1024, NH);
  k2_ktv<<<g2, 256, 0, stream>>>(phi_k, vv, kTv, sumk);
  k25_pack<<<(NH * 65 * 64 + 64 * 64 + 255) / 256, 256, 0, stream>>>(kTv, sumk, Wm, kTvT, WmP);
  k3_out<<<(NROWS + 63) / 64, 256, 0, stream>>>(phi_q, vv, kTvT, WmP, bm, out);
}

// Round 4
// 449.007 us; speedup vs baseline: 2.8532x; 1.5926x over previous
//
#include <hip/hip_runtime.h>
#include <hip/hip_bf16.h>

#define NROWS 100000
#define NH 8
#define RPC 1568     // k1 rows per chunk (64 chunks)
#define NSUB 49      // 32-row subtiles per chunk
#define K2CH 98      // k2 chunks of 1024 rows

typedef short s16x8 __attribute__((ext_vector_type(8)));
typedef float f32x4 __attribute__((ext_vector_type(4)));
typedef unsigned short u16;

__device__ __forceinline__ u16 f2bf(float f) {
  union { float f; unsigned u; } x; x.f = f;
  unsigned r = (x.u + 0x7FFFu + ((x.u >> 16) & 1u)) >> 16;
  return (u16)r;
}
__device__ __forceinline__ float bf2f(u16 b) {
  union { unsigned u; float f; } x; x.u = ((unsigned)b) << 16;
  return x.f;
}

// ---------------------------------------------------------------------------
// Kernel 0: pack W to bf16 MFMA A-fragments.
// Frag id = ((h*2+c2)*48 + s)*64 + lane.  s<32: qk tile t=s>>3, ks=s&7
// (Wq if c2==0 else Wk, col=t*16+(lane&15)); s>=32: v tile tv=(s>>3)-4,
// col = c2*32 + tv*16 + (lane&15).  Elems: k = ks*32 + (lane>>4)*8 + j.
// ---------------------------------------------------------------------------
__global__ __launch_bounds__(256) void k0_pack(
    const float* __restrict__ Wq, const float* __restrict__ Wk,
    const float* __restrict__ Wv, u16* __restrict__ Wp)
{
  int t = blockIdx.x * 256 + threadIdx.x;   // 0..49151
  int lane = t & 63;
  int rest = t >> 6;
  int s = rest % 48;
  int hc = rest / 48;
  int c2 = hc & 1, h = hc >> 1;
  int ml = lane & 15, sgk = lane >> 4;
  const float* W; int col, ks;
  if (s < 32) { int tl = s >> 3; ks = s & 7; W = c2 ? Wk : Wq; col = tl * 16 + ml; }
  else        { int tv = (s >> 3) - 4; ks = s & 7; W = Wv; col = c2 * 32 + tv * 16 + ml; }
  int k0 = ks * 32 + sgk * 8;
  u16 o[8];
#pragma unroll
  for (int j = 0; j < 8; j++)
    o[j] = f2bf(W[((size_t)h * 256 + k0 + j) * 64 + col]);
  ushort4* dst = (ushort4*)(Wp + (size_t)t * 8);
  dst[0] = make_ushort4(o[0], o[1], o[2], o[3]);
  dst[1] = make_ushort4(o[4], o[5], o[6], o[7]);
}

// ---------------------------------------------------------------------------
// Kernel 1: persistent per-head blocks. Grid 512 = 8 heads x 64 row-chunks,
// blockIdx = rc + 64*h  (=> blockIdx%8 == rc%8: all 8 heads of a chunk share
// an XCD's L2 for the x stream). W(q|k) resident in 128 VGPRs; W(v) in LDS.
// 32-row subtiles, x prefetched into regs one subtile ahead. All global
// stores are contiguous full-line writes via LDS transpose staging.
// ---------------------------------------------------------------------------
__global__ __launch_bounds__(256, 2) void k1_gemm_phi(
    const float* __restrict__ x, const u16* __restrict__ Wp,
    const float* __restrict__ bq, const float* __restrict__ bk,
    const float* __restrict__ bv, const float* __restrict__ nsc,
    u16* __restrict__ phi_q, u16* __restrict__ phi_k, u16* __restrict__ vout)
{
  __shared__ u16 xs[32 * 256];        // 16 KB, chunk-swizzled
  __shared__ u16 vws[32 * 64 * 8];    // 32 KB, v W-fragments
  __shared__ u16 stq[4 * 16 * 72];    // 9216 B, wave-local q/k store staging
  __shared__ u16 stv[32 * 72];        // 4608 B, cross-wave v store staging
  __shared__ float biasl[192];        // [q|k|v]

  const int tid = threadIdx.x;
  const int wv = tid >> 6, lane = tid & 63;
  const int c2 = wv & 1, rg = wv >> 1;
  const int m = lane & 15, sg = lane >> 4;
  const int rc = blockIdx.x & 63, h = blockIdx.x >> 6;
  const int n0 = rc * RPC;

  if (tid < 192) {
    const float* bp = tid < 64 ? bq : (tid < 128 ? bk : bv);
    biasl[tid] = bp[h * 64 + (tid & 63)];
  }

  // resident qk W fragments: 32 x s16x8 = 128 VGPR
  const u16* wb = Wp + (size_t)(h * 2 + c2) * (48 * 64 * 8);
  s16x8 wq[4][8];
#pragma unroll
  for (int t = 0; t < 4; t++)
#pragma unroll
    for (int ks = 0; ks < 8; ks++)
      wq[t][ks] = *(const s16x8*)(wb + ((t * 8 + ks) * 64 + lane) * 8);

  // v W fragments -> LDS (tiles 0..3 across both c2 regions)
#pragma unroll
  for (int i2 = 0; i2 < 8; i2++) {
    int u = tid + i2 * 256;           // 0..2047 = (tl*8+ks)*64 + ln
    int tl = u >> 9, ks = (u >> 6) & 7, ln = u & 63;
    const u16* src = Wp + ((size_t)(h * 2 + (tl >> 1)) * 48 + 32 + (tl & 1) * 8 + ks) * (64 * 8)
                     + (size_t)ln * 8;
    *(s16x8*)(vws + (size_t)u * 8) = *(const s16x8*)src;
  }

  // stage subtile 0
#pragma unroll
  for (int i = 0; i < 4; i++) {
    int cu = tid + i * 256;
    int row = cu >> 5, c = cu & 31;
    int n = n0 + row; if (n >= NROWS) n = NROWS - 1;
    const float* src = x + (size_t)n * 256 + c * 8;
    float4 f0 = *(const float4*)src;
    float4 f1 = *(const float4*)(src + 4);
    s16x8 pk;
    pk[0] = (short)f2bf(f0.x); pk[1] = (short)f2bf(f0.y);
    pk[2] = (short)f2bf(f0.z); pk[3] = (short)f2bf(f0.w);
    pk[4] = (short)f2bf(f1.x); pk[5] = (short)f2bf(f1.y);
    pk[6] = (short)f2bf(f1.z); pk[7] = (short)f2bf(f1.w);
    *(s16x8*)(xs + row * 256 + ((c ^ (row & 7)) * 8)) = pk;
  }
  __syncthreads();

  const float inv_denom = 1.0f / (fabsf(nsc[0]) + 1e-6f);
  u16* const xbase = xs + (rg * 16 + m) * 256;
  const int sw = m & 7;

  for (int s = 0; s < NSUB; s++) {
    // issue x loads for s+1 (regs; consumed after the barrier)
    float4 xl[8];
    if (s + 1 < NSUB) {
      int nb = n0 + (s + 1) * 32;
#pragma unroll
      for (int i = 0; i < 4; i++) {
        int cu = tid + i * 256;
        int row = cu >> 5, c = cu & 31;
        int n = nb + row; if (n >= NROWS) n = NROWS - 1;
        const float* src = x + (size_t)n * 256 + c * 8;
        xl[i * 2]     = *(const float4*)src;
        xl[i * 2 + 1] = *(const float4*)(src + 4);
      }
    }

    // MFMA: 4 qk tiles (resident W) + 2 v tiles (LDS W)
    f32x4 aq[4], av[2];
#pragma unroll
    for (int t = 0; t < 4; t++) aq[t] = (f32x4){0.f, 0.f, 0.f, 0.f};
    av[0] = (f32x4){0.f, 0.f, 0.f, 0.f};
    av[1] = (f32x4){0.f, 0.f, 0.f, 0.f};
#pragma unroll
    for (int ks = 0; ks < 8; ks++) {
      s16x8 bf = *(const s16x8*)(xbase + (((ks * 4 + sg) ^ sw) * 8));
#pragma unroll
      for (int t = 0; t < 4; t++)
        aq[t] = __builtin_amdgcn_mfma_f32_16x16x32_bf16(wq[t][ks], bf, aq[t], 0, 0, 0);
      s16x8 vw0 = *(const s16x8*)(vws + (((c2 * 2 + 0) * 8 + ks) * 64 + lane) * 8);
      s16x8 vw1 = *(const s16x8*)(vws + (((c2 * 2 + 1) * 8 + ks) * 64 + lane) * 8);
      av[0] = __builtin_amdgcn_mfma_f32_16x16x32_bf16(vw0, bf, av[0], 0, 0, 0);
      av[1] = __builtin_amdgcn_mfma_f32_16x16x32_bf16(vw1, bf, av[1], 0, 0, 0);
    }

    // epilogue: bias + phi + in-wave norm (row = rg*16+m, ch = t*16+sg*4+r)
    f32x4 bqk[4], bvv[2];
#pragma unroll
    for (int t = 0; t < 4; t++) bqk[t] = *(const f32x4*)&biasl[c2 * 64 + t * 16 + sg * 4];
#pragma unroll
    for (int tv = 0; tv < 2; tv++) bvv[tv] = *(const f32x4*)&biasl[128 + c2 * 32 + tv * 16 + sg * 4];

    float vq[4][4];
    float s2 = 0.f, s4 = 0.f;
#pragma unroll
    for (int t = 0; t < 4; t++)
#pragma unroll
      for (int r = 0; r < 4; r++) {
        float y = (fmaxf(aq[t][r] + bqk[t][r], 0.f) + 1e-6f) * inv_denom;
        float y2 = y * y;
        vq[t][r] = y2;
        s2 += y2; s4 += y2 * y2;
      }
    s2 += __shfl_xor(s2, 16); s2 += __shfl_xor(s2, 32);
    s4 += __shfl_xor(s4, 16); s4 += __shfl_xor(s4, 32);
    float sc = sqrtf(s2) / (sqrtf(s4) + 1e-12f);

    {
      u16* sq = stq + wv * 1152 + m * 72;
#pragma unroll
      for (int t = 0; t < 4; t++)
        *(ushort4*)(sq + ((t + m) & 3) * 16 + sg * 4) =
          make_ushort4(f2bf(vq[t][0] * sc), f2bf(vq[t][1] * sc),
                       f2bf(vq[t][2] * sc), f2bf(vq[t][3] * sc));
      int rowl = rg * 16 + m;
      u16* sv = stv + rowl * 72;
#pragma unroll
      for (int tv = 0; tv < 2; tv++) {
        int tc = c2 * 2 + tv;
        f32x4 a = av[tv], b = bvv[tv];
        *(ushort4*)(sv + ((tc + rowl) & 3) * 16 + sg * 4) =
          make_ushort4(f2bf(a[0] + b[0]), f2bf(a[1] + b[1]),
                       f2bf(a[2] + b[2]), f2bf(a[3] + b[3]));
      }
    }
    // flush q/k (wave-local: same-wave ds_write->ds_read, no barrier)
    {
      int r_ = lane >> 2, tc = lane & 3;
      const u16* a = stq + wv * 1152 + r_ * 72 + ((tc + r_) & 3) * 16;
      s16x8 p0 = *(const s16x8*)a;
      s16x8 p1 = *(const s16x8*)(a + 8);
      int n = n0 + s * 32 + rg * 16 + r_;
      if (n < NROWS) {
        u16* dst = (c2 ? phi_k : phi_q) + ((size_t)h * NROWS + n) * 64 + tc * 16;
        *(s16x8*)dst = p0;
        *(s16x8*)(dst + 8) = p1;
      }
    }
    __syncthreads();   // xs reads + stv writes complete

    // flush v (cross-wave data now visible)
    {
      int row = wv * 8 + (lane >> 3);
      int hc8 = lane & 7, tc = hc8 >> 1, half = hc8 & 1;
      const u16* a = stv + row * 72 + ((tc + row) & 3) * 16 + half * 8;
      s16x8 pv = *(const s16x8*)a;
      int n = n0 + s * 32 + row;
      if (n < NROWS)
        *(s16x8*)(vout + ((size_t)h * NROWS + n) * 64 + tc * 16 + half * 8) = pv;
    }
    // write xs for s+1 from prefetched regs
    if (s + 1 < NSUB) {
#pragma unroll
      for (int i = 0; i < 4; i++) {
        int cu = tid + i * 256;
        int row = cu >> 5, c = cu & 31;
        float4 f0 = xl[i * 2], f1 = xl[i * 2 + 1];
        s16x8 pk;
        pk[0] = (short)f2bf(f0.x); pk[1] = (short)f2bf(f0.y);
        pk[2] = (short)f2bf(f0.z); pk[3] = (short)f2bf(f0.w);
        pk[4] = (short)f2bf(f1.x); pk[5] = (short)f2bf(f1.y);
        pk[6] = (short)f2bf(f1.z); pk[7] = (short)f2bf(f1.w);
        *(s16x8*)(xs + row * 256 + ((c ^ (row & 7)) * 8)) = pk;
      }
    }
    __syncthreads();   // new xs visible; stv flushed before next overwrite
  }
}

// ---------------------------------------------------------------------------
// Kernel 2: partial kT_v per 1024-row chunk (no atomics). Double-buffered
// LDS transpose, 1 barrier per 64-row subtile. sum_k via ones-column MFMA.
// P layout: [rc][h][65][64], rows 0..63 = kTv^T (d-major), row 64 = sum_k.
// ---------------------------------------------------------------------------
__global__ __launch_bounds__(256) void k2_ktv(
    const u16* __restrict__ phi_k, const u16* __restrict__ vin,
    float* __restrict__ P)
{
  __shared__ u16 pkT[2][64][72];
  __shared__ u16 vT[2][64][72];
  const int tid = threadIdx.x;
  const int h = blockIdx.y;
  const int r0 = blockIdx.x * 1024;
  const int wv = tid >> 6, lane = tid & 63;
  const int m = lane & 15, sg = lane >> 4;
  const int c4 = (tid & 15) * 4, rgp = tid >> 4;

  const u16* pkb = phi_k + (size_t)h * (NROWS * 64);
  const u16* vb  = vin  + (size_t)h * (NROWS * 64);

  f32x4 acc[4];
#pragma unroll
  for (int t = 0; t < 4; t++) acc[t] = (f32x4){0.f, 0.f, 0.f, 0.f};
  f32x4 accs = (f32x4){0.f, 0.f, 0.f, 0.f};
  s16x8 onesf;
#pragma unroll
  for (int j = 0; j < 8; j++) onesf[j] = (m == 0) ? (short)0x3F80 : (short)0;

  ushort4 pk4[4], vv4[4];
#define K2_LOAD(sub)                                                        \
  {                                                                         \
    int nb = r0 + (sub) * 64 + rgp * 4;                                     \
    _Pragma("unroll")                                                       \
    for (int i = 0; i < 4; i++) {                                           \
      int n = nb + i;                                                       \
      if (n < NROWS) {                                                      \
        pk4[i] = *(const ushort4*)(pkb + (size_t)n * 64 + c4);              \
        vv4[i] = *(const ushort4*)(vb  + (size_t)n * 64 + c4);              \
      } else {                                                              \
        pk4[i] = make_ushort4(0, 0, 0, 0);                                  \
        vv4[i] = make_ushort4(0, 0, 0, 0);                                  \
      }                                                                     \
    }                                                                       \
  }
#define K2_WRITE(buf)                                                       \
  {                                                                         \
    *(ushort4*)&pkT[buf][c4 + 0][rgp * 4] = make_ushort4(pk4[0].x, pk4[1].x, pk4[2].x, pk4[3].x); \
    *(ushort4*)&pkT[buf][c4 + 1][rgp * 4] = make_ushort4(pk4[0].y, pk4[1].y, pk4[2].y, pk4[3].y); \
    *(ushort4*)&pkT[buf][c4 + 2][rgp * 4] = make_ushort4(pk4[0].z, pk4[1].z, pk4[2].z, pk4[3].z); \
    *(ushort4*)&pkT[buf][c4 + 3][rgp * 4] = make_ushort4(pk4[0].w, pk4[1].w, pk4[2].w, pk4[3].w); \
    *(ushort4*)&vT[buf][c4 + 0][rgp * 4]  = make_ushort4(vv4[0].x, vv4[1].x, vv4[2].x, vv4[3].x); \
    *(ushort4*)&vT[buf][c4 + 1][rgp * 4]  = make_ushort4(vv4[0].y, vv4[1].y, vv4[2].y, vv4[3].y); \
    *(ushort4*)&vT[buf][c4 + 2][rgp * 4]  = make_ushort4(vv4[0].z, vv4[1].z, vv4[2].z, vv4[3].z); \
    *(ushort4*)&vT[buf][c4 + 3][rgp * 4]  = make_ushort4(vv4[0].w, vv4[1].w, vv4[2].w, vv4[3].w); \
  }

  K2_LOAD(0); K2_WRITE(0);
  __syncthreads();

  for (int sub = 0; sub < 16; sub++) {
    int cur = sub & 1;
    if (sub + 1 < 16) K2_LOAD(sub + 1);
#pragma unroll
    for (int ks = 0; ks < 2; ks++) {
      s16x8 af = *(const s16x8*)&pkT[cur][wv * 16 + m][ks * 32 + sg * 8];
#pragma unroll
      for (int t = 0; t < 4; t++) {
        s16x8 bfv = *(const s16x8*)&vT[cur][t * 16 + m][ks * 32 + sg * 8];
        acc[t] = __builtin_amdgcn_mfma_f32_16x16x32_bf16(af, bfv, acc[t], 0, 0, 0);
      }
      accs = __builtin_amdgcn_mfma_f32_16x16x32_bf16(af, onesf, accs, 0, 0, 0);
    }
    if (sub + 1 < 16) K2_WRITE(cur ^ 1);
    __syncthreads();
  }

  float* pb = P + (size_t)(blockIdx.x * NH + h) * (65 * 64);
  int mm = wv * 16 + sg * 4;
#pragma unroll
  for (int t = 0; t < 4; t++)
#pragma unroll
    for (int r = 0; r < 4; r++)
      pb[(t * 16 + m) * 64 + mm + r] = acc[t][r];
  if (m == 0)
#pragma unroll
    for (int r = 0; r < 4; r++)
      pb[64 * 64 + mm + r] = accs[r];
}

// ---------------------------------------------------------------------------
// Kernel 2.5: reduce partials -> bf16 kTvT[8][65][64]; pack WmP[e][d]=Wm[d][e]
// ---------------------------------------------------------------------------
__global__ __launch_bounds__(256) void k25_pack(
    const float* __restrict__ P, const float* __restrict__ Wm,
    u16* __restrict__ kTvT, u16* __restrict__ WmP)
{
  int idx = blockIdx.x * 256 + threadIdx.x;
  if (idx < NH * 65 * 64) {
    float s = 0.f;
    for (int rcc = 0; rcc < K2CH; rcc++)
      s += P[(size_t)rcc * (NH * 65 * 64) + idx];
    kTvT[idx] = f2bf(s);
  } else if (idx < NH * 65 * 64 + 64 * 64) {
    int j = idx - NH * 65 * 64;
    WmP[j] = f2bf(Wm[(j & 63) * 64 + (j >> 6)]);
  }
}

// ---------------------------------------------------------------------------
// Kernel 3: out = mean_h( (phi_q@kTv[h]) / (phi_q.sum_k[h]+1e-6) )
//           + vbar@Wm + bm; Lorentz lift. Zero LDS, zero barriers.
// ---------------------------------------------------------------------------
__global__ __launch_bounds__(256) void k3_out(
    const u16* __restrict__ phi_q, const u16* __restrict__ vin,
    const u16* __restrict__ kTvT, const u16* __restrict__ WmP,
    const float* __restrict__ bm, float* __restrict__ out)
{
  const int tid = threadIdx.x;
  const int wv = tid >> 6, lane = tid & 63;
  const int m = lane & 15, sg = lane >> 4;
  const int n0 = blockIdx.x * 64;
  const int rw = wv * 16;
  const int n = n0 + rw + m;

  float bmv[4];
#pragma unroll
  for (int t = 0; t < 4; t++) bmv[t] = bm[t * 16 + m];

  s16x8 vbf[2];
#pragma unroll
  for (int ks = 0; ks < 2; ks++) {
    float a[8];
#pragma unroll
    for (int j = 0; j < 8; j++) a[j] = 0.f;
#pragma unroll
    for (int h = 0; h < NH; h++) {
      s16x8 v8 = *(const s16x8*)(vin + (size_t)h * (NROWS * 64) + (size_t)n * 64
                                 + ks * 32 + sg * 8);
#pragma unroll
      for (int j = 0; j < 8; j++) a[j] += bf2f((u16)v8[j]);
    }
#pragma unroll
    for (int j = 0; j < 8; j++) vbf[ks][j] = (short)f2bf(a[j] * 0.125f);
  }

  f32x4 zero4 = {0.f, 0.f, 0.f, 0.f};
  s16x8 zero8 = {0, 0, 0, 0, 0, 0, 0, 0};
  f32x4 osum[4];
#pragma unroll
  for (int t = 0; t < 4; t++) osum[t] = zero4;

  for (int h = 0; h < NH; h++) {
    const u16* pqb = phi_q + (size_t)h * (NROWS * 64) + (size_t)n * 64;
    const u16* kb = kTvT + (size_t)h * (65 * 64);
    f32x4 accn[4];
#pragma unroll
    for (int t = 0; t < 4; t++) accn[t] = zero4;
    f32x4 accd = zero4;
#pragma unroll
    for (int ks = 0; ks < 2; ks++) {
      s16x8 aq = *(const s16x8*)(pqb + ks * 32 + sg * 8);
#pragma unroll
      for (int t = 0; t < 4; t++) {
        s16x8 bfv = *(const s16x8*)(kb + (size_t)(t * 16 + m) * 64 + ks * 32 + sg * 8);
        accn[t] = __builtin_amdgcn_mfma_f32_16x16x32_bf16(aq, bfv, accn[t], 0, 0, 0);
      }
      s16x8 bd = zero8;
      if (m == 0)
        bd = *(const s16x8*)(kb + (size_t)64 * 64 + ks * 32 + sg * 8);
      accd = __builtin_amdgcn_mfma_f32_16x16x32_bf16(aq, bd, accd, 0, 0, 0);
    }
#pragma unroll
    for (int r = 0; r < 4; r++) {
      float den = __shfl(accd[r], lane & 48);
      float rinv = 1.0f / (den + 1e-6f);
#pragma unroll
      for (int t = 0; t < 4; t++) osum[t][r] += accn[t][r] * rinv;
    }
  }

  f32x4 accr[4];
#pragma unroll
  for (int t = 0; t < 4; t++) accr[t] = zero4;
#pragma unroll
  for (int ks = 0; ks < 2; ks++)
#pragma unroll
    for (int t = 0; t < 4; t++) {
      s16x8 bw = *(const s16x8*)(WmP + (size_t)(t * 16 + m) * 64 + ks * 32 + sg * 8);
      accr[t] = __builtin_amdgcn_mfma_f32_16x16x32_bf16(vbf[ks], bw, accr[t], 0, 0, 0);
    }

#pragma unroll
  for (int r = 0; r < 4; r++) {
    int nn = n0 + rw + sg * 4 + r;
    float v4[4];
    float ssq = 0.f;
#pragma unroll
    for (int t = 0; t < 4; t++) {
      float o = osum[t][r] * 0.125f + accr[t][r] + bmv[t];
      v4[t] = o;
      ssq += o * o;
    }
    ssq += __shfl_xor(ssq, 1);
    ssq += __shfl_xor(ssq, 2);
    ssq += __shfl_xor(ssq, 4);
    ssq += __shfl_xor(ssq, 8);
    if (nn < NROWS) {
      if (m == 0) out[(size_t)nn * 65] = sqrtf(ssq + 1.0f);
#pragma unroll
      for (int t = 0; t < 4; t++)
        out[(size_t)nn * 65 + 1 + t * 16 + m] = v4[t];
    }
  }
}

// ---------------------------------------------------------------------------
extern "C" void kernel_launch(void* const* d_in, const int* in_sizes, int n_in,
                              void* d_out, int out_size, void* d_ws, size_t ws_size,
                              hipStream_t stream) {
  const float* x   = (const float*)d_in[0];
  const float* Wq  = (const float*)d_in[1];
  const float* bq  = (const float*)d_in[2];
  const float* Wk  = (const float*)d_in[3];
  const float* bk  = (const float*)d_in[4];
  const float* Wv  = (const float*)d_in[5];
  const float* bv  = (const float*)d_in[6];
  const float* nsc = (const float*)d_in[7];
  const float* Wm  = (const float*)d_in[8];
  const float* bm  = (const float*)d_in[9];
  float* out = (float*)d_out;

  char* ws = (char*)d_ws;
  const size_t PHI_BYTES = (size_t)NROWS * NH * 64 * 2;   // 102,400,000
  u16* phi_q = (u16*)(ws);
  u16* phi_k = (u16*)(ws + PHI_BYTES);
  u16* vv    = (u16*)(ws + 2 * PHI_BYTES);
  u16* Wp    = (u16*)(ws + 3 * PHI_BYTES);                // 786,432 B
  char* p    = ws + 3 * PHI_BYTES + 786432;
  float* P   = (float*)(p);                               // 98*8*65*64*4 = 13,066,240 B
  u16* kTvT  = (u16*)(p + 13066240);                      // 66,560 B
  u16* WmP   = (u16*)(p + 13066240 + 66560);              // 8,192 B

  k0_pack<<<192, 256, 0, stream>>>(Wq, Wk, Wv, Wp);
  k1_gemm_phi<<<512, 256, 0, stream>>>(x, Wp, bq, bk, bv, nsc, phi_q, phi_k, vv);
  dim3 g2(K2CH, NH);
  k2_ktv<<<g2, 256, 0, stream>>>(phi_k, vv, P);
  k25_pack<<<(NH * 65 * 64 + 64 * 64 + 255) / 256, 256, 0, stream>>>(P, Wm, kTvT, WmP);
  k3_out<<<(NROWS + 63) / 64, 256, 0, stream>>>(phi_q, vv, kTvT, WmP, bm, out);
}